// Round 7
// baseline (559.269 us; speedup 1.0000x reference)
//
#include <hip/hip_runtime.h>
#include <hip/hip_cooperative_groups.h>
#include <stdint.h>

namespace cg = cooperative_groups;

#define BATCH   16384
#define D_IN    2000
#define HID     100
#define BN_EPS_VAL 1e-5f

#define BK      32
#define BN_PAD  128
#define KT      63                      // ceil(2000/32)
#define W1Q_ELEMS (KT * BN_PAD * BK)    // 258048
#define NBLK    512
#define NTHR    256

typedef float f32x4 __attribute__((ext_vector_type(4)));
typedef short bf16x8 __attribute__((ext_vector_type(8)));

// workspace: F[] floats at byte 0 (F[0..4] absmaxes, F[16..116) b1_int,
// F[116..316) w2_int, u32 S1 at F+520, u32 S2 at F+620 — all zeroed in-kernel);
// ushort w1q[63][128][32] at byte 4096.
#define WS_W1Q_OFF 4096

__device__ __forceinline__ unsigned short f2bf(float q) {
    return (unsigned short)(__float_as_uint(q) >> 16);   // exact for small ints
}

__device__ __forceinline__ void block_atomic_maxf(float v, float* dst) {
#pragma unroll
    for (int off = 32; off > 0; off >>= 1)
        v = fmaxf(v, __shfl_xor(v, off, 64));
    __shared__ float sm[4];
    const int w = threadIdx.x >> 6;
    if ((threadIdx.x & 63) == 0) sm[w] = v;
    __syncthreads();
    if (threadIdx.x == 0) {
        float m = fmaxf(fmaxf(sm[0], sm[1]), fmaxf(sm[2], sm[3]));
        atomicMax((unsigned int*)dst, __float_as_uint(m)); // all values >= 0
    }
    __syncthreads();
}

// ONE cooperative kernel: absmax -> quant-prep -> GEMM1(MFMA)+relu ->
// 8-bit quant + BN stats -> BN+GEMM2+relu -> final 8-bit quant.
// 512 blocks x 256 thr (2 blocks/CU guaranteed: 27.8 KB LDS, lb(256,2)).
// Each block owns 32 rows; h stays in LDS end-to-end (no h1/q2 globals).
__global__ __launch_bounds__(NTHR, 2)
void k_all(const float* __restrict__ sig, const float* __restrict__ W1,
           const float* __restrict__ b1, const float* __restrict__ W2,
           const float* __restrict__ b2, const float* __restrict__ gamma,
           const float* __restrict__ beta, float* __restrict__ F,
           unsigned short* __restrict__ w1q, float* __restrict__ out) {
    cg::grid_group grid = cg::this_grid();
    const int t    = threadIdx.x;
    const int bid  = blockIdx.x;
    const int lane = t & 63;
    const int wid  = t >> 6;

    __shared__ float redf[2][16][113];   // phase C reduction; overlaid later
    __shared__ float hbuf[32][104];      // per-block h rows (then q codes)
    float* flat = &redf[0][0][0];
    unsigned int* ls1 = (unsigned int*)flat;        // [100]
    unsigned int* ls2 = ls1 + 128;                  // [100]
    float* sw   = flat + 256;                       // [200] w2_int
    float* smu  = flat + 456;                       // [100]
    float* sr   = flat + 556;                       // [100]
    float* sg   = flat + 656;                       // [100]
    float* sb   = flat + 756;                       // [100]
    float* ssc  = flat + 856;                       // [8]
    float* obuf = flat + 864;                       // [64]
    unsigned int* S1 = (unsigned int*)(F + 520);
    unsigned int* S2 = (unsigned int*)(F + 620);

    // ---- P0: zero the F scalar region (atomics depend on it) ----
    if (bid == 0)
        for (int i = t; i < 1024; i += NTHR) F[i] = 0.0f;
    grid.sync();

    // ---- A: absmax(sig) [all blocks], absmax(W1) [blocks 0..15], absmax(W2) ----
    {
        float m = 0.0f;
        const float4* p = (const float4*)sig;
#pragma unroll 4
        for (int i = bid * NTHR + t; i < BATCH * D_IN / 4; i += NBLK * NTHR) {
            float4 v = p[i];
            m = fmaxf(m, fmaxf(fmaxf(fabsf(v.x), fabsf(v.y)),
                               fmaxf(fabsf(v.z), fabsf(v.w))));
        }
        block_atomic_maxf(m, &F[0]);
        if (bid < 16) {
            float mw = 0.0f;
            const float4* q = (const float4*)W1;
            for (int i = bid * NTHR + t; i < HID * D_IN / 4; i += 16 * NTHR) {
                float4 v = q[i];
                mw = fmaxf(mw, fmaxf(fmaxf(fabsf(v.x), fabsf(v.y)),
                                     fmaxf(fabsf(v.z), fabsf(v.w))));
            }
            block_atomic_maxf(mw, &F[1]);
        }
        if (bid == 16) {
            float mw = (t < 2 * HID) ? fabsf(W2[t]) : 0.0f;
            block_atomic_maxf(mw, &F[2]);
        }
    }
    grid.sync();

    // ---- B: quantize W1 -> tiled bf16 w1q; b1_int; w2_int ----
    {
        const float ws1 = F[1];
        for (int i = bid * NTHR + t; i < W1Q_ELEMS; i += NBLK * NTHR) {
            const int kt = i >> 12;          // /(128*32)
            const int r  = i & 4095;
            const int n  = r >> 5;
            const int kk = r & 31;
            const int k  = kt * 32 + kk;
            float qv = 0.0f;
            if (n < HID && k < D_IN)
                qv = fminf(fmaxf(rintf(W1[n * D_IN + k] / ws1), -2.0f), 1.0f);
            w1q[i] = f2bf(qv);
        }
        if (bid == 17 && t < HID) {
            const float bs = ws1 * (F[0] / 15.0f);
            F[16 + t] = fminf(fmaxf(rintf(b1[t] / bs), -2.0f), 1.0f);
        }
        if (bid == 16 && t < 2 * HID)
            F[116 + t] = fminf(fmaxf(rintf(W2[t] / F[2]), -2.0f), 1.0f);
    }
    grid.sync();

    // ---- C: GEMM1 (MFMA, 32 rows/block, 2-way K-split) + bias + relu ----
    {
        const float s1  = F[0] / 15.0f;
        const float bs1 = F[1] * s1;
        const int m0 = bid * 32;
        const int rg = wid & 1;             // 16-row group
        const int ks = wid >> 1;            // K-split half
        const int fr = lane & 15;
        const int g8 = (lane >> 4) * 8;
        const float* aptr = sig + (size_t)(m0 + rg * 16 + fr) * D_IN;

        f32x4 acc[7] = {};
#pragma unroll 2
        for (int kt = ks; kt < KT; kt += 2) {
            const int k0 = kt * BK + g8;
            union { bf16x8 v; unsigned short s[8]; } A;
            float e[8];
            if (k0 + 8 <= D_IN) {
                float4 va = *(const float4*)(aptr + k0);
                float4 vb = *(const float4*)(aptr + k0 + 4);
                e[0]=va.x; e[1]=va.y; e[2]=va.z; e[3]=va.w;
                e[4]=vb.x; e[5]=vb.y; e[6]=vb.z; e[7]=vb.w;
            } else {
#pragma unroll
                for (int j = 0; j < 8; ++j) e[j] = (k0 + j < D_IN) ? aptr[k0 + j] : 0.0f;
            }
#pragma unroll
            for (int j = 0; j < 8; ++j)
                A.s[j] = f2bf(fminf(fmaxf(rintf(e[j] / s1), -16.0f), 15.0f));

            const unsigned short* bbase = w1q + ((size_t)kt * BN_PAD + fr) * BK + g8;
#pragma unroll
            for (int tt = 0; tt < 7; ++tt) {
                bf16x8 bfr = *(const bf16x8*)(bbase + tt * 16 * BK);
                acc[tt] = __builtin_amdgcn_mfma_f32_16x16x32_bf16(A.v, bfr, acc[tt], 0, 0, 0);
            }
        }

        const int rl = (lane >> 4) * 4;     // C/D row base
        if (ks == 1) {
#pragma unroll
            for (int tt = 0; tt < 7; ++tt)
#pragma unroll
                for (int r = 0; r < 4; ++r)
                    redf[rg][rl + r][tt * 16 + fr] = acc[tt][r];
        }
        __syncthreads();

        float lmax = 0.0f;
        if (ks == 0) {
#pragma unroll
            for (int tt = 0; tt < 7; ++tt) {
                const int n = tt * 16 + fr;         // C/D col = lane&15
                if (n < HID) {
                    const float bi = F[16 + n];
#pragma unroll
                    for (int r = 0; r < 4; ++r) {   // exact-int adds: order-free
                        float h = (acc[tt][r] + redf[rg][rl + r][n] + bi) * bs1;
                        h = fmaxf(h, 0.0f);
                        hbuf[rg * 16 + rl + r][n] = h;
                        lmax = fmaxf(lmax, h);
                    }
                }
            }
        }
        block_atomic_maxf(lmax, &F[3]);
    }
    grid.sync();

    // ---- D: 8-bit quantize h (in-place, LDS) + exact integer column sums ----
    {
        if (t < 128) { ls1[t] = 0u; ls2[t] = 0u; }
        __syncthreads();
        const float s2 = F[3] / 127.0f;
        for (int i = t; i < 32 * HID; i += NTHR) {
            const int row = i / HID, c = i % HID;
            const float h = hbuf[row][c];            // >= 0
            const float q = fminf(rintf(h / s2), 127.0f);
            hbuf[row][c] = q;
            const unsigned int qi = (unsigned int)q;
            atomicAdd(&ls1[c], qi);
            atomicAdd(&ls2[c], qi * qi);
        }
        __syncthreads();
        if (t < HID) { atomicAdd(&S1[t], ls1[t]); atomicAdd(&S2[t], ls2[t]); }
    }
    grid.sync();

    // ---- E: BN stats (exact u32 sums -> double) + gemm2 constants [per block] ----
    {
        const float s2 = F[3] / 127.0f;
        if (t < HID) {
            const double sd   = (double)s2;
            const double mean = sd * ((double)S1[t] / 16384.0);
            const double ex2  = sd * sd * ((double)S2[t] / 16384.0);
            const double var  = ex2 - mean * mean;
            const float vpe   = (float)var + BN_EPS_VAL;
            smu[t] = (float)mean;
            sr[t]  = (float)(1.0 / sqrt((double)vpe));
            sg[t]  = gamma[t];
            sb[t]  = beta[t];
        }
        if (t < 2 * HID) sw[t] = F[116 + t];
        if (t == 220) {
            const float bs2 = F[2] * s2;
            ssc[0] = s2;
            ssc[1] = bs2;
            ssc[2] = fminf(fmaxf(rintf(b2[0] / bs2), -2.0f), 1.0f);
            ssc[3] = fminf(fmaxf(rintf(b2[1] / bs2), -2.0f), 1.0f);
        }
        __syncthreads();

        // ---- F: BN + GEMM2 (N=2) + relu, rows block-local ----
        float lmax = 0.0f;
        if (t < 32) {
            const float s2v = ssc[0];
            float a0 = 0.0f, a1 = 0.0f;
            for (int h = 0; h < HID; ++h) {          // same order as verified kernel
                const float q   = hbuf[t][h];
                const float x2v = q * s2v;
                const float xb  = fmaf((x2v - smu[h]) * sr[h], sg[h], sb[h]);
                const float xi  = xb / s2v;
                a0 = fmaf(xi, sw[h], a0);
                a1 = fmaf(xi, sw[HID + h], a1);
            }
            const float o0 = fmaxf((a0 + ssc[2]) * ssc[1], 0.0f);
            const float o1 = fmaxf((a1 + ssc[3]) * ssc[1], 0.0f);
            obuf[t * 2]     = o0;
            obuf[t * 2 + 1] = o1;
            lmax = fmaxf(o0, o1);
        }
        block_atomic_maxf(lmax, &F[4]);
    }
    grid.sync();

    // ---- G: final 8-bit quant_act -> d_out ----
    {
        const float s3 = F[4] / 127.0f;
        if (t < 64) {
            const float v = obuf[t];
            out[bid * 64 + t] = fminf(fmaxf(rintf(v / s3), -128.0f), 127.0f) * s3;
        }
    }
}

extern "C" void kernel_launch(void* const* d_in, const int* in_sizes, int n_in,
                              void* d_out, int out_size, void* d_ws, size_t ws_size,
                              hipStream_t stream) {
    (void)in_sizes; (void)n_in; (void)out_size; (void)ws_size;
    const float* sig   = (const float*)d_in[0];
    const float* W1    = (const float*)d_in[1];
    const float* b1    = (const float*)d_in[2];
    const float* W2    = (const float*)d_in[3];
    const float* b2    = (const float*)d_in[4];
    const float* gamma = (const float*)d_in[5];
    const float* beta  = (const float*)d_in[6];
    float* F            = (float*)d_ws;
    unsigned short* w1q = (unsigned short*)((char*)d_ws + WS_W1Q_OFF);
    float* out          = (float*)d_out;

    void* args[] = { &sig, &W1, &b1, &W2, &b2, &gamma, &beta, &F, &w1q, &out };
    hipLaunchCooperativeKernel((void*)k_all, dim3(NBLK), dim3(NTHR),
                               args, 0, stream);
}

// Round 8
// 511.376 us; speedup vs baseline: 1.0937x; 1.0937x over previous
//
#include <hip/hip_runtime.h>
#include <hip/hip_bf16.h>
#include <stdint.h>

#define BATCH   16384
#define D_IN    2000
#define HID     100
#define OUT_DIM 2
#define BN_EPS_VAL 1e-5f

#define BK      32
#define BN_PAD  128
#define KT      63                      // ceil(2000/32)
#define W1Q_ELEMS (KT * BN_PAD * BK)    // 258048
#define G1_REPS 4                       // instrumentation: gemm1 visible in top-5

typedef float f32x4 __attribute__((ext_vector_type(4)));
typedef short bf16x8 __attribute__((ext_vector_type(8)));

// ---------------- workspace layout (bytes) ----------------
// [0, 4096): float F[] scalars (zeroed by memset each launch)
//   F[0..4] absmaxes; F[16..116) b1_int; F[116..316) w2_int;
//   F[320..420) mu; F[420..520) rstd; u32 S1@F+520; u32 S2@F+620;
//   F[920..922) b2_int; F[922] b_s2
// [4096, +516096): ushort w1q[63][128][32]
// [1MB): float h1[16384][100]   [8MB): u8 q2   [10MB): float out2
#define WS_W1Q_OFF 4096
#define WS_H1_OFF  (1u << 20)
#define WS_Q2_OFF  (8u << 20)
#define WS_O2_OFF  (10u << 20)

__device__ __forceinline__ void block_atomic_maxf(float v, float* dst) {
#pragma unroll
    for (int off = 32; off > 0; off >>= 1)
        v = fmaxf(v, __shfl_xor(v, off, 64));
    __shared__ float sm[8];
    const int w = threadIdx.x >> 6;
    if ((threadIdx.x & 63) == 0) sm[w] = v;
    __syncthreads();
    if (threadIdx.x == 0) {
        const int nw = (blockDim.x + 63) >> 6;
        float m = sm[0];
        for (int i = 1; i < nw; ++i) m = fmaxf(m, sm[i]);
        atomicMax((unsigned int*)dst, __float_as_uint(m)); // all values >= 0
    }
}

// ---------------- K0: absmax of sig / W1 / W2 ----------------
__global__ __launch_bounds__(256)
void k_absmax(const float* __restrict__ sig, const float* __restrict__ W1,
              const float* __restrict__ W2, float* __restrict__ F) {
    float m = 0.0f;
    const int b = blockIdx.x;
    if (b < 2048) {
        const float4* p = (const float4*)sig;
        const int n4 = BATCH * D_IN / 4;
        for (int i = b * 256 + threadIdx.x; i < n4; i += 2048 * 256) {
            float4 v = p[i];
            m = fmaxf(m, fmaxf(fmaxf(fabsf(v.x), fabsf(v.y)),
                               fmaxf(fabsf(v.z), fabsf(v.w))));
        }
        block_atomic_maxf(m, &F[0]);
    } else if (b < 2064) {
        const float4* p = (const float4*)W1;
        const int n4 = HID * D_IN / 4;
        for (int i = (b - 2048) * 256 + threadIdx.x; i < n4; i += 16 * 256) {
            float4 v = p[i];
            m = fmaxf(m, fmaxf(fmaxf(fabsf(v.x), fabsf(v.y)),
                               fmaxf(fabsf(v.z), fabsf(v.w))));
        }
        block_atomic_maxf(m, &F[1]);
    } else {
        if (threadIdx.x < OUT_DIM * HID) m = fabsf(W2[threadIdx.x]);
        block_atomic_maxf(m, &F[2]);
    }
}

// ---------------- K1: quantize W1 (tiled bf16), b1, W2 ----------------
__global__ __launch_bounds__(256)
void k_prep(const float* __restrict__ W1, const float* __restrict__ b1,
            const float* __restrict__ W2, float* __restrict__ F,
            unsigned short* __restrict__ w1q) {
    const int tid = blockIdx.x * 256 + threadIdx.x;
    const float ws1 = F[1];
    if (tid < W1Q_ELEMS) {
        const int kt = tid >> 12;
        const int r  = tid & 4095;
        const int n  = r >> 5;
        const int kk = r & 31;
        const int k  = kt * 32 + kk;
        float q = 0.0f;
        if (n < HID && k < D_IN) {
            q = rintf(W1[n * D_IN + k] / ws1);
            q = fminf(fmaxf(q, -2.0f), 1.0f);
        }
        w1q[tid] = (unsigned short)(__float_as_uint(q) >> 16); // exact bf16
    } else if (tid < W1Q_ELEMS + HID) {
        const int h = tid - W1Q_ELEMS;
        const float s1 = F[0] / 15.0f;
        const float bs = ws1 * s1;
        F[16 + h] = fminf(fmaxf(rintf(b1[h] / bs), -2.0f), 1.0f);
    } else if (tid < W1Q_ELEMS + HID + OUT_DIM * HID) {
        const int j = tid - (W1Q_ELEMS + HID);
        const float ws2 = F[2];
        F[116 + j] = fminf(fmaxf(rintf(W2[j] / ws2), -2.0f), 1.0f);
    }
}

// ---------------- K2: GEMM1 (R2-exact LDS-staged) x G1_REPS (instrumented) ----
__global__ __launch_bounds__(256)
void k_gemm1(const float* __restrict__ sig, const unsigned short* __restrict__ w1q,
             float* __restrict__ F, float* __restrict__ h1) {
    __shared__ unsigned short As[32][40];
    __shared__ unsigned short Bs[128][40];
    const int tid  = threadIdx.x;
    const int lane = tid & 63;
    const int wid  = tid >> 6;
    const float s1  = F[0] / 15.0f;
    const float bs1 = F[1] * s1;
    const int m0 = blockIdx.x * 32;

    const int ar  = tid >> 3;
    const int akl = (tid & 7) * 4;
    const float* aptr = sig + (size_t)(m0 + ar) * D_IN + akl;

    const int rh = (wid & 1) * 16;
    const int ng = (wid >> 1) * 4;
    const int fr = lane & 15;
    const int fk = (lane >> 4) * 8;

#pragma unroll 1
    for (int rep = 0; rep < G1_REPS; ++rep) {       // idempotent repeat
        f32x4 acc[4] = {};

        for (int kt = 0; kt < KT; ++kt) {
            const int kbase = kt * BK;
            float4 v;
            if (kbase + akl < D_IN) v = *(const float4*)(aptr + kbase);
            else                    v = make_float4(0.f, 0.f, 0.f, 0.f);
            ushort4 qa;
            {
                float q;
                q = fminf(fmaxf(rintf(v.x / s1), -16.f), 15.f); qa.x = (unsigned short)(__float_as_uint(q) >> 16);
                q = fminf(fmaxf(rintf(v.y / s1), -16.f), 15.f); qa.y = (unsigned short)(__float_as_uint(q) >> 16);
                q = fminf(fmaxf(rintf(v.z / s1), -16.f), 15.f); qa.z = (unsigned short)(__float_as_uint(q) >> 16);
                q = fminf(fmaxf(rintf(v.w / s1), -16.f), 15.f); qa.w = (unsigned short)(__float_as_uint(q) >> 16);
            }
            *(ushort4*)&As[ar][akl] = qa;
            {
                const uint4* bt = (const uint4*)(w1q + (size_t)kt * (BN_PAD * BK));
                uint4 b0 = bt[tid];
                uint4 b1v = bt[tid + 256];
                *(uint4*)&Bs[tid >> 2][(tid & 3) * 8] = b0;
                *(uint4*)&Bs[(tid + 256) >> 2][(tid & 3) * 8] = b1v;
            }
            __syncthreads();
            bf16x8 a = *(const bf16x8*)&As[rh + fr][fk];
#pragma unroll
            for (int t = 0; t < 4; ++t) {
                bf16x8 b = *(const bf16x8*)&Bs[(ng + t) * 16 + fr][fk];
                acc[t] = __builtin_amdgcn_mfma_f32_16x16x32_bf16(a, b, acc[t], 0, 0, 0);
            }
            __syncthreads();
        }

        float lmax = 0.0f;
#pragma unroll
        for (int t = 0; t < 4; ++t) {
            const int n = (ng + t) * 16 + fr;
            if (n < HID) {
                const float bi = F[16 + n];
#pragma unroll
                for (int r = 0; r < 4; ++r) {
                    const int m = m0 + rh + (lane >> 4) * 4 + r;
                    float h = (acc[t][r] + bi) * bs1;
                    h = fmaxf(h, 0.0f);
                    h1[(size_t)m * HID + n] = h;
                    lmax = fmaxf(lmax, h);
                }
            }
        }
        block_atomic_maxf(lmax, &F[3]);
        __syncthreads();
    }
}

// ---------------- K3: quantize h1 -> int8 codes + exact column sums ----------------
__global__ __launch_bounds__(256)
void k_quant_h(const float* __restrict__ h1, unsigned char* __restrict__ q2,
               const float* __restrict__ F, unsigned int* __restrict__ S1,
               unsigned int* __restrict__ S2) {
    __shared__ unsigned int ls1[HID], ls2[HID];
    if (threadIdx.x < HID) { ls1[threadIdx.x] = 0u; ls2[threadIdx.x] = 0u; }
    __syncthreads();
    const float s2 = F[3] / 127.0f;
    const int base = blockIdx.x * 6400;          // 64 rows x 100 cols
#pragma unroll 5
    for (int it = 0; it < 25; ++it) {
        const int idx = base + it * 256 + threadIdx.x;
        const float h = h1[idx];                 // >= 0
        const int q = (int)fminf(rintf(h / s2), 127.0f);
        q2[idx] = (unsigned char)q;
        const int c = idx % HID;
        atomicAdd(&ls1[c], (unsigned int)q);
        atomicAdd(&ls2[c], (unsigned int)(q * q));
    }
    __syncthreads();
    if (threadIdx.x < HID) {
        atomicAdd(&S1[threadIdx.x], ls1[threadIdx.x]);
        atomicAdd(&S2[threadIdx.x], ls2[threadIdx.x]);
    }
}

// ---------------- K4: BN stats + b2 quant ----------------
__global__ void k_bnprep(const float* __restrict__ b2, float* __restrict__ F,
                         const unsigned int* __restrict__ S1,
                         const unsigned int* __restrict__ S2) {
    const int t = threadIdx.x;
    const float s2  = F[3] / 127.0f;
    const float ws2 = F[2];
    const float bs2 = ws2 * s2;
    if (t < HID) {
        const double sd   = (double)s2;
        const double mean = sd * ((double)S1[t] / 16384.0);
        const double ex2  = sd * sd * ((double)S2[t] / 16384.0);
        const double var  = ex2 - mean * mean;
        const float varf  = (float)var;
        const float vpe   = varf + BN_EPS_VAL;
        const float rf    = (float)(1.0 / sqrt((double)vpe));
        F[320 + t] = (float)mean;
        F[420 + t] = rf;
    }
    if (t < OUT_DIM) F[920 + t] = fminf(fmaxf(rintf(b2[t] / bs2), -2.0f), 1.0f);
    if (t == 64) F[922] = bs2;
}

// ---------------- K5: BN + GEMM2 (N=2, VALU) + relu + absmax ----------------
__global__ __launch_bounds__(256)
void k_gemm2(const unsigned char* __restrict__ q2, float* __restrict__ F,
             const float* __restrict__ gamma, const float* __restrict__ beta,
             float* __restrict__ out2) {
    __shared__ float sw[2 * HID], smu[HID], sr[HID], sg[HID], sb[HID];
    __shared__ float ssc[4];
    const int t = threadIdx.x;
    if (t < 2 * HID) sw[t] = F[116 + t];
    if (t < HID) { smu[t] = F[320 + t]; sr[t] = F[420 + t]; sg[t] = gamma[t]; sb[t] = beta[t]; }
    if (t == 200) ssc[0] = F[3] / 127.0f;  // s2
    if (t == 201) ssc[1] = F[922];         // b_s2
    if (t == 202) ssc[2] = F[920];         // b2_int[0]
    if (t == 203) ssc[3] = F[921];         // b2_int[1]
    __syncthreads();
    const int row = blockIdx.x * 256 + t;
    const unsigned int* rp = (const unsigned int*)(q2 + (size_t)row * HID);
    const float s2 = ssc[0];
    float a0 = 0.0f, a1 = 0.0f;
#pragma unroll
    for (int j = 0; j < 25; ++j) {
        const unsigned int u = rp[j];
#pragma unroll
        for (int bb = 0; bb < 4; ++bb) {
            const int h = j * 4 + bb;
            const float q = (float)((u >> (8 * bb)) & 255u);
            const float x2v = q * s2;
            const float xb  = fmaf((x2v - smu[h]) * sr[h], sg[h], sb[h]);
            const float xi  = xb / s2;
            a0 = fmaf(xi, sw[h], a0);
            a1 = fmaf(xi, sw[HID + h], a1);
        }
    }
    const float o0 = fmaxf((a0 + ssc[2]) * ssc[1], 0.0f);
    const float o1 = fmaxf((a1 + ssc[3]) * ssc[1], 0.0f);
    out2[row * 2 + 0] = o0;
    out2[row * 2 + 1] = o1;
    block_atomic_maxf(fmaxf(o0, o1), &F[4]);
}

// ---------------- K6: final 8-bit quant_act ----------------
__global__ __launch_bounds__(256)
void k_final(const float* __restrict__ out2, const float* __restrict__ F,
             float* __restrict__ out) {
    const int i = blockIdx.x * 256 + threadIdx.x;     // 8192 float4s
    const float s3 = F[4] / 127.0f;
    float4 v = ((const float4*)out2)[i];
    float4 r;
    r.x = fminf(fmaxf(rintf(v.x / s3), -128.f), 127.f) * s3;
    r.y = fminf(fmaxf(rintf(v.y / s3), -128.f), 127.f) * s3;
    r.z = fminf(fmaxf(rintf(v.z / s3), -128.f), 127.f) * s3;
    r.w = fminf(fmaxf(rintf(v.w / s3), -128.f), 127.f) * s3;
    ((float4*)out)[i] = r;
}

extern "C" void kernel_launch(void* const* d_in, const int* in_sizes, int n_in,
                              void* d_out, int out_size, void* d_ws, size_t ws_size,
                              hipStream_t stream) {
    const float* sig   = (const float*)d_in[0];
    const float* W1    = (const float*)d_in[1];
    const float* b1    = (const float*)d_in[2];
    const float* W2    = (const float*)d_in[3];
    const float* b2    = (const float*)d_in[4];
    const float* gamma = (const float*)d_in[5];
    const float* beta  = (const float*)d_in[6];

    float* F = (float*)d_ws;
    unsigned short* w1q = (unsigned short*)((char*)d_ws + WS_W1Q_OFF);
    float* h1           = (float*)((char*)d_ws + WS_H1_OFF);
    unsigned char* q2   = (unsigned char*)((char*)d_ws + WS_Q2_OFF);
    float* o2           = (float*)((char*)d_ws + WS_O2_OFF);
    unsigned int* S1    = (unsigned int*)(F + 520);
    unsigned int* S2    = (unsigned int*)(F + 620);

    hipMemsetAsync(d_ws, 0, 4096, stream);
    k_absmax <<<2065, 256, 0, stream>>>(sig, W1, W2, F);
    k_prep   <<<1010, 256, 0, stream>>>(W1, b1, W2, F, w1q);
    k_gemm1  <<<512,  256, 0, stream>>>(sig, w1q, F, h1);
    k_quant_h<<<256,  256, 0, stream>>>(h1, q2, F, S1, S2);
    k_bnprep <<<1,    128, 0, stream>>>(b2, F, S1, S2);
    k_gemm2  <<<64,   256, 0, stream>>>(q2, F, gamma, beta, o2);
    k_final  <<<32,   256, 0, stream>>>(o2, F, (float*)d_out);
}

// Round 9
// 286.874 us; speedup vs baseline: 1.9495x; 1.7826x over previous
//
#include <hip/hip_runtime.h>
#include <hip/hip_bf16.h>
#include <stdint.h>

#define BATCH   16384
#define D_IN    2000
#define HID     100
#define OUT_DIM 2
#define BN_EPS_VAL 1e-5f

#define BK      32
#define BN_PAD  128
#define KT      63                      // ceil(2000/32)
#define W1Q_ELEMS (KT * BN_PAD * BK)    // 258048
#define NPREPA  16128                   // blocks for A-frag prep (64512 chunks / 4 waves)

typedef float f32x4 __attribute__((ext_vector_type(4)));
typedef short bf16x8 __attribute__((ext_vector_type(8)));

// ---------------- workspace layout (bytes) ----------------
// [0, 4096): float F[] scalars (zeroed by memset each launch)
//   F[0..4] absmaxes; F[16..116) b1_int; F[116..316) w2_int;
//   F[320..420) mu; F[420..520) rstd; u32 S1@F+520; u32 S2@F+620;
//   F[920..922) b2_int; F[922] b_s2
// [4096, +516096): ushort w1q[63][128][32]   (bf16 bits, K-tile-major)
// [1MB): float h1[16384][100]
// [8MB): u8 q2[16384][100]
// [10MB): float out2[16384][2]
// [16MB, +66MB): ushort qa[1024*63 chunks][64 lanes][8]  (A in MFMA frag order)
#define WS_W1Q_OFF 4096
#define WS_H1_OFF  (1u << 20)
#define WS_Q2_OFF  (8u << 20)
#define WS_O2_OFF  (10u << 20)
#define WS_QA_OFF  (16u << 20)

__device__ __forceinline__ unsigned short f2bf(float q) {
    return (unsigned short)(__float_as_uint(q) >> 16);   // exact for small ints
}

__device__ __forceinline__ void block_atomic_maxf(float v, float* dst) {
#pragma unroll
    for (int off = 32; off > 0; off >>= 1)
        v = fmaxf(v, __shfl_xor(v, off, 64));
    __shared__ float sm[8];
    const int w = threadIdx.x >> 6;
    if ((threadIdx.x & 63) == 0) sm[w] = v;
    __syncthreads();
    if (threadIdx.x == 0) {
        const int nw = (blockDim.x + 63) >> 6;
        float m = sm[0];
        for (int i = 1; i < nw; ++i) m = fmaxf(m, sm[i]);
        atomicMax((unsigned int*)dst, __float_as_uint(m)); // all values >= 0
    }
}

// ---------------- K0: absmax of sig / W1 / W2 ----------------
__global__ __launch_bounds__(256)
void k_absmax(const float* __restrict__ sig, const float* __restrict__ W1,
              const float* __restrict__ W2, float* __restrict__ F) {
    float m = 0.0f;
    const int b = blockIdx.x;
    if (b < 2048) {
        const float4* p = (const float4*)sig;
        const int n4 = BATCH * D_IN / 4;
        for (int i = b * 256 + threadIdx.x; i < n4; i += 2048 * 256) {
            float4 v = p[i];
            m = fmaxf(m, fmaxf(fmaxf(fabsf(v.x), fabsf(v.y)),
                               fmaxf(fabsf(v.z), fabsf(v.w))));
        }
        block_atomic_maxf(m, &F[0]);
    } else if (b < 2064) {
        const float4* p = (const float4*)W1;
        const int n4 = HID * D_IN / 4;
        for (int i = (b - 2048) * 256 + threadIdx.x; i < n4; i += 16 * 256) {
            float4 v = p[i];
            m = fmaxf(m, fmaxf(fmaxf(fabsf(v.x), fabsf(v.y)),
                               fmaxf(fabsf(v.z), fabsf(v.w))));
        }
        block_atomic_maxf(m, &F[1]);
    } else {
        if (threadIdx.x < OUT_DIM * HID) m = fabsf(W2[threadIdx.x]);
        block_atomic_maxf(m, &F[2]);
    }
}

// ---------------- K1: prep — A-frag quantize-swizzle + W1/b1/W2 quantize ----
// bid < NPREPA: one wave per (mt,kt) chunk. lane = kg*16+fr holds
// sig[mt*16+fr][kt*32+kg*8 .. +8] quantized to 5-bit codes as bf16 —
// exactly the mfma_16x16x32 A-fragment layout (same codes as the verified
// in-loop quantize; moved here bit-identically). Store 16B/lane contiguous.
__global__ __launch_bounds__(256)
void k_prep(const float* __restrict__ sig, const float* __restrict__ W1,
            const float* __restrict__ b1, const float* __restrict__ W2,
            float* __restrict__ F, unsigned short* __restrict__ w1q,
            unsigned short* __restrict__ qa) {
    const int bid = blockIdx.x;
    const int t = threadIdx.x;
    if (bid < NPREPA) {
        const int c  = bid * 4 + (t >> 6);      // chunk 0..64511
        const int mt = c / KT, kt = c - mt * KT;
        const int lane = t & 63;
        const int fr = lane & 15, kg = lane >> 4;
        const int row = mt * 16 + fr;
        const int k   = kt * 32 + kg * 8;
        const float s1 = F[0] / 15.0f;
        float e[8];
        if (k + 8 <= D_IN) {
            const float4 va = *(const float4*)(sig + (size_t)row * D_IN + k);
            const float4 vb = *(const float4*)(sig + (size_t)row * D_IN + k + 4);
            e[0]=va.x; e[1]=va.y; e[2]=va.z; e[3]=va.w;
            e[4]=vb.x; e[5]=vb.y; e[6]=vb.z; e[7]=vb.w;
        } else {
#pragma unroll
            for (int j = 0; j < 8; ++j) e[j] = 0.0f;   // k>=2000 only (kt=62,kg>=2)
        }
        union { ushort4 u4[2]; unsigned short s[8]; } A;
#pragma unroll
        for (int j = 0; j < 8; ++j)
            A.s[j] = f2bf(fminf(fmaxf(rintf(e[j] / s1), -16.0f), 15.0f));
        ushort4* dst = (ushort4*)(qa + ((size_t)c * 64 + lane) * 8);
        dst[0] = A.u4[0];
        dst[1] = A.u4[1];
    } else {
        const int tid = (bid - NPREPA) * 256 + t;
        const float ws1 = F[1];
        if (tid < W1Q_ELEMS) {
            const int kt = tid >> 12;
            const int r  = tid & 4095;
            const int n  = r >> 5;
            const int kk = r & 31;
            const int k  = kt * 32 + kk;
            float q = 0.0f;
            if (n < HID && k < D_IN) {
                q = rintf(W1[n * D_IN + k] / ws1);
                q = fminf(fmaxf(q, -2.0f), 1.0f);
            }
            w1q[tid] = f2bf(q);
        } else if (tid < W1Q_ELEMS + HID) {
            const int h = tid - W1Q_ELEMS;
            const float bs = ws1 * (F[0] / 15.0f);
            F[16 + h] = fminf(fmaxf(rintf(b1[h] / bs), -2.0f), 1.0f);
        } else if (tid < W1Q_ELEMS + HID + OUT_DIM * HID) {
            const int j = tid - (W1Q_ELEMS + HID);
            F[116 + j] = fminf(fmaxf(rintf(W2[j] / F[2]), -2.0f), 1.0f);
        }
    }
}

// ---------------- K2: GEMM1 — pure load+MFMA stream, no LDS/barriers in loop ----
// 512 blocks x 256 thr (4 waves). Block owns 32 rows (2 mts); wave ks owns a
// contiguous kt chunk {0-15,16-31,32-47,48-62}. B-frags loaded once per kt,
// reused for both mts. Exact-integer partials -> order-free LDS reduce.
__global__ __launch_bounds__(256)
void k_gemm1(const unsigned short* __restrict__ qa,
             const unsigned short* __restrict__ w1q,
             float* __restrict__ F, float* __restrict__ h1) {
    __shared__ float red[3][32][113];
    const int t    = threadIdx.x;
    const int lane = t & 63;
    const int ks   = t >> 6;
    const float bs1 = F[1] * (F[0] / 15.0f);
    const int mt0 = blockIdx.x * 2;
    const int fr  = lane & 15;
    const int g8  = (lane >> 4) * 8;

    const int kt0 = ks * 16;
    const int kt1 = (ks == 3) ? KT : kt0 + 16;

    f32x4 accA[7] = {}, accB[7] = {};

    for (int kt = kt0; kt < kt1; ++kt) {
        const bf16x8 a0 = *(const bf16x8*)(qa + (((size_t)mt0 * KT + kt) * 64 + lane) * 8);
        const bf16x8 a1 = *(const bf16x8*)(qa + (((size_t)(mt0 + 1) * KT + kt) * 64 + lane) * 8);
        const unsigned short* bbase = w1q + ((size_t)kt * BN_PAD + fr) * BK + g8;
#pragma unroll
        for (int tt = 0; tt < 7; ++tt) {
            const bf16x8 b = *(const bf16x8*)(bbase + tt * 16 * BK);
            accA[tt] = __builtin_amdgcn_mfma_f32_16x16x32_bf16(a0, b, accA[tt], 0, 0, 0);
            accB[tt] = __builtin_amdgcn_mfma_f32_16x16x32_bf16(a1, b, accB[tt], 0, 0, 0);
        }
    }

    const int rl = (lane >> 4) * 4;         // C/D row base: (lane>>4)*4 + r
    if (ks != 0) {
#pragma unroll
        for (int tt = 0; tt < 7; ++tt)
#pragma unroll
            for (int r = 0; r < 4; ++r) {
                red[ks - 1][rl + r][tt * 16 + fr]      = accA[tt][r];
                red[ks - 1][16 + rl + r][tt * 16 + fr] = accB[tt][r];
            }
    }
    __syncthreads();

    float lmax = 0.0f;
    if (ks == 0) {
        const int m0 = blockIdx.x * 32;
#pragma unroll
        for (int tt = 0; tt < 7; ++tt) {
            const int n = tt * 16 + fr;     // C/D col = lane&15
            if (n < HID) {
                const float bi = F[16 + n];
#pragma unroll
                for (int r = 0; r < 4; ++r) {   // exact-int adds: order-free
                    float hA = (accA[tt][r] + red[0][rl + r][n] + red[1][rl + r][n]
                                + red[2][rl + r][n] + bi) * bs1;
                    float hB = (accB[tt][r] + red[0][16 + rl + r][n] + red[1][16 + rl + r][n]
                                + red[2][16 + rl + r][n] + bi) * bs1;
                    hA = fmaxf(hA, 0.0f);
                    hB = fmaxf(hB, 0.0f);
                    h1[(size_t)(m0 + rl + r) * HID + n]      = hA;
                    h1[(size_t)(m0 + 16 + rl + r) * HID + n] = hB;
                    lmax = fmaxf(lmax, fmaxf(hA, hB));
                }
            }
        }
    }
    block_atomic_maxf(lmax, &F[3]);
}

// ---------------- K3: quantize h1 -> int8 codes + exact column sums ----------------
__global__ __launch_bounds__(256)
void k_quant_h(const float* __restrict__ h1, unsigned char* __restrict__ q2,
               const float* __restrict__ F, unsigned int* __restrict__ S1,
               unsigned int* __restrict__ S2) {
    __shared__ unsigned int ls1[HID], ls2[HID];
    if (threadIdx.x < HID) { ls1[threadIdx.x] = 0u; ls2[threadIdx.x] = 0u; }
    __syncthreads();
    const float s2 = F[3] / 127.0f;
    const int base = blockIdx.x * 6400;          // 64 rows x 100 cols
#pragma unroll 5
    for (int it = 0; it < 25; ++it) {
        const int idx = base + it * 256 + threadIdx.x;
        const float h = h1[idx];                 // >= 0
        const int q = (int)fminf(rintf(h / s2), 127.0f);
        q2[idx] = (unsigned char)q;
        const int c = idx % HID;
        atomicAdd(&ls1[c], (unsigned int)q);
        atomicAdd(&ls2[c], (unsigned int)(q * q));
    }
    __syncthreads();
    if (threadIdx.x < HID) {
        atomicAdd(&S1[threadIdx.x], ls1[threadIdx.x]);
        atomicAdd(&S2[threadIdx.x], ls2[threadIdx.x]);
    }
}

// ---------------- K4: BN stats + b2 quant ----------------
__global__ void k_bnprep(const float* __restrict__ b2, float* __restrict__ F,
                         const unsigned int* __restrict__ S1,
                         const unsigned int* __restrict__ S2) {
    const int t = threadIdx.x;
    const float s2  = F[3] / 127.0f;
    const float bs2 = F[2] * s2;
    if (t < HID) {
        const double sd   = (double)s2;
        const double mean = sd * ((double)S1[t] / 16384.0);
        const double ex2  = sd * sd * ((double)S2[t] / 16384.0);
        const double var  = ex2 - mean * mean;
        const float vpe   = (float)var + BN_EPS_VAL;
        F[320 + t] = (float)mean;
        F[420 + t] = (float)(1.0 / sqrt((double)vpe));
    }
    if (t < OUT_DIM) F[920 + t] = fminf(fmaxf(rintf(b2[t] / bs2), -2.0f), 1.0f);
    if (t == 64) F[922] = bs2;
}

// ---------------- K5: BN + GEMM2 (N=2, VALU) + relu + absmax ----------------
__global__ __launch_bounds__(256)
void k_gemm2(const unsigned char* __restrict__ q2, float* __restrict__ F,
             const float* __restrict__ gamma, const float* __restrict__ beta,
             float* __restrict__ out2) {
    __shared__ float sw[2 * HID], smu[HID], sr[HID], sg[HID], sb[HID];
    __shared__ float ssc[4];
    const int t = threadIdx.x;
    if (t < 2 * HID) sw[t] = F[116 + t];
    if (t < HID) { smu[t] = F[320 + t]; sr[t] = F[420 + t]; sg[t] = gamma[t]; sb[t] = beta[t]; }
    if (t == 200) ssc[0] = F[3] / 127.0f;
    if (t == 201) ssc[1] = F[922];
    if (t == 202) ssc[2] = F[920];
    if (t == 203) ssc[3] = F[921];
    __syncthreads();
    const int row = blockIdx.x * 256 + t;
    const unsigned int* rp = (const unsigned int*)(q2 + (size_t)row * HID);
    const float s2 = ssc[0];
    float a0 = 0.0f, a1 = 0.0f;
#pragma unroll
    for (int j = 0; j < 25; ++j) {
        const unsigned int u = rp[j];
#pragma unroll
        for (int bb = 0; bb < 4; ++bb) {
            const int h = j * 4 + bb;
            const float q = (float)((u >> (8 * bb)) & 255u);
            const float x2v = q * s2;
            const float xb  = fmaf((x2v - smu[h]) * sr[h], sg[h], sb[h]);
            const float xi  = xb / s2;
            a0 = fmaf(xi, sw[h], a0);
            a1 = fmaf(xi, sw[HID + h], a1);
        }
    }
    const float o0 = fmaxf((a0 + ssc[2]) * ssc[1], 0.0f);
    const float o1 = fmaxf((a1 + ssc[3]) * ssc[1], 0.0f);
    out2[row * 2 + 0] = o0;
    out2[row * 2 + 1] = o1;
    block_atomic_maxf(fmaxf(o0, o1), &F[4]);
}

// ---------------- K6: final 8-bit quant_act ----------------
__global__ __launch_bounds__(256)
void k_final(const float* __restrict__ out2, const float* __restrict__ F,
             float* __restrict__ out) {
    const int i = blockIdx.x * 256 + threadIdx.x;     // 8192 float4s
    const float s3 = F[4] / 127.0f;
    float4 v = ((const float4*)out2)[i];
    float4 r;
    r.x = fminf(fmaxf(rintf(v.x / s3), -128.f), 127.f) * s3;
    r.y = fminf(fmaxf(rintf(v.y / s3), -128.f), 127.f) * s3;
    r.z = fminf(fmaxf(rintf(v.z / s3), -128.f), 127.f) * s3;
    r.w = fminf(fmaxf(rintf(v.w / s3), -128.f), 127.f) * s3;
    ((float4*)out)[i] = r;
}

extern "C" void kernel_launch(void* const* d_in, const int* in_sizes, int n_in,
                              void* d_out, int out_size, void* d_ws, size_t ws_size,
                              hipStream_t stream) {
    const float* sig   = (const float*)d_in[0];
    const float* W1    = (const float*)d_in[1];
    const float* b1    = (const float*)d_in[2];
    const float* W2    = (const float*)d_in[3];
    const float* b2    = (const float*)d_in[4];
    const float* gamma = (const float*)d_in[5];
    const float* beta  = (const float*)d_in[6];

    float* F = (float*)d_ws;
    unsigned short* w1q = (unsigned short*)((char*)d_ws + WS_W1Q_OFF);
    float* h1           = (float*)((char*)d_ws + WS_H1_OFF);
    unsigned char* q2   = (unsigned char*)((char*)d_ws + WS_Q2_OFF);
    float* o2           = (float*)((char*)d_ws + WS_O2_OFF);
    unsigned short* qa  = (unsigned short*)((char*)d_ws + WS_QA_OFF);
    unsigned int* S1    = (unsigned int*)(F + 520);
    unsigned int* S2    = (unsigned int*)(F + 620);

    hipMemsetAsync(d_ws, 0, 4096, stream);
    k_absmax <<<2065, 256, 0, stream>>>(sig, W1, W2, F);
    k_prep   <<<NPREPA + 1010, 256, 0, stream>>>(sig, W1, b1, W2, F, w1q, qa);
    k_gemm1  <<<512,  256, 0, stream>>>(qa, w1q, F, h1);
    k_quant_h<<<256,  256, 0, stream>>>(h1, q2, F, S1, S2);
    k_bnprep <<<1,    128, 0, stream>>>(b2, F, S1, S2);
    k_gemm2  <<<64,   256, 0, stream>>>(q2, F, gamma, beta, o2);
    k_final  <<<32,   256, 0, stream>>>(o2, F, (float*)d_out);
}